// Round 7
// baseline (495.182 us; speedup 1.0000x reference)
//
#include <hip/hip_runtime.h>

// DGCNN on MI355X — round 18: R17 NT-load null -> FETCH is hint-immune; but
// law dur(k3) ~= FETCH/1.37TB/s holds across R12-R17. So reduce FETCH itself:
// gather h1 (256B/row) instead of B3 (512B/row) and recompute the B3 tile
// on the fly with MFMA (k3 MfmaUtil only 24%). Gather 800->400MB.
// Bitwise-exact: k2 stores exact fp32 h1 (i<NN), drops B3; k3 replicates k2's
// old GEMM2 (same frags nt 8..15, same per-acc kc/3-MFMA order) -> b3acc ==
// old B3 bit-for-bit; e routed C-layout -> LDS scratch -> A-frag (k2's hF
// pattern, same-wave). absmax must stay exactly 4.768372e-07.
// LDS: W4H 32K + escratch 32K + ashare 8K + gshare 8K = 80KB -> 2 blocks/CU
// (occupancy proven non-lever in R15). W3Xb + W4L stream from L2.
//   concat(a, b-a) @ W + bias = a @ (Wt-Wb) + b @ Wb + bias
//   conv2 gathers h1 with NODE ids -> only h1[0:N] rows needed

#define NN 100000
#define KNB 16
#define EE (NN * KNB)

// weight fragment bases (units of 512 ushorts = one 64-lane x 8-bf16 frag)
#define W2F 0     // W2  [64][64]   : 2 kc x 4 nt  = 8
#define W3F 8     // W3X [64][256]  : 2 kc x 16 nt = 32  (cols 0-127: W3t-W3b, 128-255: W3b)
#define W4F 40    // W4  [128][128] : 4 kc x 8 nt  = 32
#define W5F 72    // W5  [128][128] : 4 kc x 8 nt  = 32
#define W6F 104   // W6  [128][48p] : 4 kc x 3 nt  = 12
#define NFRAG 116

typedef float floatx4 __attribute__((ext_vector_type(4)));
typedef __bf16 bf16x8 __attribute__((ext_vector_type(8)));

static __device__ __forceinline__ unsigned f2bf_rne_u(float f) {
    unsigned u = __float_as_uint(f);
    return (u + 0x7FFFu + ((u >> 16) & 1u)) >> 16;
}
static __device__ __forceinline__ float bfu2f(unsigned h) {
    return __uint_as_float(h << 16);
}

// split a pair of fp32 into packed bf16 hi (truncate) + bf16 lo (RNE of exact
// residual). hp = {lo16: a_hi, hi16: b_hi}; one v_perm_b32 per pack.
static __device__ __forceinline__ void split_pack2(float a, float b,
                                                   unsigned& hp, unsigned& lp) {
    unsigned ua = __float_as_uint(a), ub = __float_as_uint(b);
    hp = __builtin_amdgcn_perm(ub, ua, 0x07060302u);        // [b.b3 b.b2 a.b3 a.b2]
    float ra = a - __uint_as_float(ua & 0xFFFF0000u);       // exact residual
    float rb = b - __uint_as_float(ub & 0xFFFF0000u);
    unsigned la = __float_as_uint(ra), lb = __float_as_uint(rb);
    la = la + 0x7FFFu + ((la >> 16) & 1u);                  // RNE round point
    lb = lb + 0x7FFFu + ((lb >> 16) & 1u);
    lp = __builtin_amdgcn_perm(lb, la, 0x07060302u);
}

// split 8 fp32 -> bf16x8 hi + bf16x8 lo
static __device__ __forceinline__ void split8(float4 f0, float4 f1,
                                              bf16x8& ah, bf16x8& al) {
    unsigned hd[4], ld[4];
    split_pack2(f0.x, f0.y, hd[0], ld[0]);
    split_pack2(f0.z, f0.w, hd[1], ld[1]);
    split_pack2(f1.x, f1.y, hd[2], ld[2]);
    split_pack2(f1.z, f1.w, hd[3], ld[3]);
    uint4 H = {hd[0], hd[1], hd[2], hd[3]};
    uint4 L = {ld[0], ld[1], ld[2], ld[3]};
    ah = __builtin_bit_cast(bf16x8, H);
    al = __builtin_bit_cast(bf16x8, L);
}

// ---------------- KW: pre-split all weights into frag-ordered bf16 hi/lo ------
// Frag (kc,nt): lane l holds W[kc*32 + (l>>4)*8 + j][nt*16 + (l&15)], j=0..7.
__global__ __launch_bounds__(256) void kw_kernel(
    const float* __restrict__ W2, const float* __restrict__ W3,
    const float* __restrict__ W4, const float* __restrict__ W5,
    const float* __restrict__ W6,
    unsigned short* __restrict__ WH, unsigned short* __restrict__ WL)
{
    int d = blockIdx.x * 256 + threadIdx.x;
    if (d >= NFRAG * 64) return;
    int f = d >> 6, l = d & 63, c = l & 15, q = l >> 4;
    float v[8];
    if (f < W3F) {                    // W2 [64][64]
        int fx = f - W2F, kc = fx >> 2, nt = fx & 3;
        int k0 = kc * 32 + q * 8, n = nt * 16 + c;
#pragma unroll
        for (int j = 0; j < 8; ++j) v[j] = W2[(k0 + j) * 64 + n];
    } else if (f < W4F) {             // W3X [64][256]
        int fx = f - W3F, kc = fx >> 4, nt = fx & 15;
        int k0 = kc * 32 + q * 8, n = nt * 16 + c;
#pragma unroll
        for (int j = 0; j < 8; ++j) {
            int k = k0 + j;
            v[j] = (n < 128) ? (W3[k * 128 + n] - W3[(64 + k) * 128 + n])
                             : W3[(64 + k) * 128 + (n - 128)];
        }
    } else if (f < W5F) {             // W4 [128][128]
        int fx = f - W4F, kc = fx >> 3, nt = fx & 7;
        int k0 = kc * 32 + q * 8, n = nt * 16 + c;
#pragma unroll
        for (int j = 0; j < 8; ++j) v[j] = W4[(k0 + j) * 128 + n];
    } else if (f < W6F) {             // W5 [128][128]
        int fx = f - W5F, kc = fx >> 3, nt = fx & 7;
        int k0 = kc * 32 + q * 8, n = nt * 16 + c;
#pragma unroll
        for (int j = 0; j < 8; ++j) v[j] = W5[(k0 + j) * 128 + n];
    } else {                          // W6 [128][40] padded to 48
        int fx = f - W6F, kc = fx / 3, nt = fx % 3;
        int k0 = kc * 32 + q * 8, n = nt * 16 + c;
#pragma unroll
        for (int j = 0; j < 8; ++j)
            v[j] = (n < 40) ? W6[(k0 + j) * 40 + n] : 0.0f;
    }
    unsigned hs[8], ls[8];
#pragma unroll
    for (int j = 0; j < 8; ++j) {
        unsigned h = f2bf_rne_u(v[j]);
        float r = v[j] - bfu2f(h);
        hs[j] = h;
        ls[j] = f2bf_rne_u(r);
    }
    uint4 H, L;
    H.x = hs[0] | (hs[1] << 16); H.y = hs[2] | (hs[3] << 16);
    H.z = hs[4] | (hs[5] << 16); H.w = hs[6] | (hs[7] << 16);
    L.x = ls[0] | (ls[1] << 16); L.y = ls[2] | (ls[3] << 16);
    L.z = ls[4] | (ls[5] << 16); L.w = ls[6] | (ls[7] << 16);
    *(uint4*)(WH + (size_t)d * 8) = H;
    *(uint4*)(WL + (size_t)d * 8) = L;
}

// ---------------- K1: A1 = x@(W1t-W1b)+b1, B1 = x@W1b ----------------
__global__ __launch_bounds__(256) void k1_kernel(
    const float* __restrict__ x, const float* __restrict__ W1,
    const float* __restrict__ b1, float* __restrict__ A1, float* __restrict__ B1)
{
    int gid = blockIdx.x * 256 + threadIdx.x;
    int n = gid >> 6;
    int j = gid & 63;
    const float* xr = x + n * 16;
    float acc_a = b1[j];
    float acc_b = 0.0f;
#pragma unroll
    for (int k = 0; k < 16; ++k) {
        float xv = xr[k];
        float wt = W1[k * 64 + j];
        float wb = W1[(16 + k) * 64 + j];
        acc_a = fmaf(xv, wt - wb, acc_a);
        acc_b = fmaf(xv, wb, acc_b);
    }
    A1[n * 64 + j] = acc_a;
    B1[n * 64 + j] = acc_b;
}

// ---------------- K2 (MFMA): 64 rows/block --------------------
// R18: GEMM2 halves (nt 0..7, A3 only); h1 (exact fp32 hF values) stored to
// global for k3's regather. B3 no longer computed or stored.
__global__ __launch_bounds__(256) void k2_kernel(
    const int* __restrict__ col,
    const float* __restrict__ A1, const float* __restrict__ B1,
    const unsigned short* __restrict__ WH, const unsigned short* __restrict__ WL,
    const float* __restrict__ b2, const float* __restrict__ b3,
    float* __restrict__ A3, float* __restrict__ H1)
{
    __shared__ __align__(16) float tF[8 * 512];   // 16 KB, frag-contig fp32
    __shared__ __align__(16) float hF[8 * 512];   // 16 KB
    const int t = threadIdx.x;
    const int i0 = blockIdx.x * 64;

    // phase A: t[row] = relu(A1[i>>4] + B1[col[i]]) -> tF frag layout
    {
        const int row = t & 63, part = t >> 6;
        int i = i0 + row;                 // tail reads valid (i < EE), stores guarded
        int nn = i >> 4;
        int ci = col[i];
        const float* ar = A1 + (size_t)nn * 64 + part * 16;
        const float* br = B1 + (size_t)ci * 64 + part * 16;
        int mt = row >> 4, m = row & 15, kc = part >> 1;
        float* base = tF + (mt * 2 + kc) * 512 + m * 8;
#pragma unroll
        for (int h = 0; h < 2; ++h) {
            int qq = (part & 1) * 2 + h;
            float4 a0 = *(const float4*)(ar + h * 8);
            float4 b0 = *(const float4*)(br + h * 8);
            float4 a1 = *(const float4*)(ar + h * 8 + 4);
            float4 b1v = *(const float4*)(br + h * 8 + 4);
            float4 r0, r1;
            r0.x = fmaxf(a0.x + b0.x, 0.0f); r0.y = fmaxf(a0.y + b0.y, 0.0f);
            r0.z = fmaxf(a0.z + b0.z, 0.0f); r0.w = fmaxf(a0.w + b0.w, 0.0f);
            r1.x = fmaxf(a1.x + b1v.x, 0.0f); r1.y = fmaxf(a1.y + b1v.y, 0.0f);
            r1.z = fmaxf(a1.z + b1v.z, 0.0f); r1.w = fmaxf(a1.w + b1v.w, 0.0f);
            *(float4*)(base + qq * 128) = r0;
            *(float4*)(base + qq * 128 + 4) = r1;
        }
    }
    __syncthreads();

    const int w = __builtin_amdgcn_readfirstlane(t >> 6);   // wave = m-tile
    const int lane = t & 63;

    // GEMM1: h-tile rows w*16..+15; acc1[nt=0..3]
    floatx4 acc1[4];
#pragma unroll
    for (int nt = 0; nt < 4; ++nt) acc1[nt] = (floatx4){0.f, 0.f, 0.f, 0.f};
#pragma unroll
    for (int kc = 0; kc < 2; ++kc) {
        const float* ap = tF + (w * 2 + kc) * 512 + lane * 8;
        bf16x8 ah, al;
        split8(*(const float4*)ap, *(const float4*)(ap + 4), ah, al);
#pragma unroll
        for (int nt = 0; nt < 4; ++nt) {
            size_t fb = (size_t)(W2F + kc * 4 + nt) * 512 + lane * 8;
            bf16x8 bh = __builtin_bit_cast(bf16x8, *(const uint4*)(WH + fb));
            bf16x8 bl = __builtin_bit_cast(bf16x8, *(const uint4*)(WL + fb));
            acc1[nt] = __builtin_amdgcn_mfma_f32_16x16x32_bf16(ah, bh, acc1[nt], 0, 0, 0);
            acc1[nt] = __builtin_amdgcn_mfma_f32_16x16x32_bf16(ah, bl, acc1[nt], 0, 0, 0);
            acc1[nt] = __builtin_amdgcn_mfma_f32_16x16x32_bf16(al, bh, acc1[nt], 0, 0, 0);
        }
    }
    // h = relu(acc1 + b2) -> hF frag layout (wave-local rows -> no barrier)
    // + store exact fp32 h1 rows to global (i<NN) for k3's regather
    {
        const int qq = lane >> 4, cc = lane & 15;
#pragma unroll
        for (int nt = 0; nt < 4; ++nt) {
            float bv = b2[nt * 16 + cc];
            int colIdx = nt * 16 + cc;
            int kc2 = colIdx >> 5, q2 = (colIdx >> 3) & 3, jj = cc & 7;
            float* dst = hF + (w * 2 + kc2) * 512 + q2 * 128 + jj;
#pragma unroll
            for (int r = 0; r < 4; ++r) {
                float hv = fmaxf(acc1[nt][r] + bv, 0.0f);
                dst[(qq * 4 + r) * 8] = hv;
                int i = i0 + w * 16 + qq * 4 + r;
                if (i < NN) H1[(size_t)i * 64 + colIdx] = hv;
            }
        }
    }
    // GEMM2 (halved): [16 x 64] @ W3X[:,0:128]; acc2[nt=0..7] -> A3 only
    floatx4 acc2[8];
#pragma unroll
    for (int nt = 0; nt < 8; ++nt) acc2[nt] = (floatx4){0.f, 0.f, 0.f, 0.f};
#pragma unroll
    for (int kc = 0; kc < 2; ++kc) {
        const float* ap = hF + (w * 2 + kc) * 512 + lane * 8;
        bf16x8 ah, al;
        split8(*(const float4*)ap, *(const float4*)(ap + 4), ah, al);
#pragma unroll
        for (int nt = 0; nt < 8; ++nt) {
            size_t fb = (size_t)(W3F + kc * 16 + nt) * 512 + lane * 8;
            bf16x8 bh = __builtin_bit_cast(bf16x8, *(const uint4*)(WH + fb));
            bf16x8 bl = __builtin_bit_cast(bf16x8, *(const uint4*)(WL + fb));
            acc2[nt] = __builtin_amdgcn_mfma_f32_16x16x32_bf16(ah, bh, acc2[nt], 0, 0, 0);
            acc2[nt] = __builtin_amdgcn_mfma_f32_16x16x32_bf16(ah, bl, acc2[nt], 0, 0, 0);
            acc2[nt] = __builtin_amdgcn_mfma_f32_16x16x32_bf16(al, bh, acc2[nt], 0, 0, 0);
        }
    }
    {
        const int qq = lane >> 4, cc = lane & 15;
#pragma unroll
        for (int nt = 0; nt < 8; ++nt) {
            int n = nt * 16 + cc;
            float bv = b3[n];
#pragma unroll
            for (int r = 0; r < 4; ++r) {
                int i = i0 + w * 16 + qq * 4 + r;
                if (i < NN) A3[(size_t)i * 128 + n] = acc2[nt][r] + bv;
            }
        }
    }
}

// ---------------- K3 (fused): h1-gather -> B3 on the fly -> edge-GEMM ----------
// Block = 16 nodes, 4 waves. Per node-pair: gather h1 rows (256B each, half of
// B3's 512B), MFMA-recompute the B3 tile (bitwise == k2's old B3: same frags
// nt 8..15, same per-acc order), e = relu(A3+b3acc) C-layout -> escratch ->
// A-frag -> W4 GEMM. Half-col pipelining keeps escratch at 8KB/wave.
__global__ __launch_bounds__(256, 2) void k3_kernel(
    const int* __restrict__ col,
    const float* __restrict__ A3, const float* __restrict__ H1,
    const unsigned short* __restrict__ WH, const unsigned short* __restrict__ WL,
    const float* __restrict__ b4, const float* __restrict__ b5,
    const float* __restrict__ b6, float* __restrict__ out)
{
    __shared__ __align__(16) unsigned short wlds[16384];  // 32 KB: W4 HI frags
    __shared__ __align__(16) float escratch[8192];        // 32 KB: per-wave e tiles
    __shared__ __align__(16) float ashare[2048];          // 8 KB: A3 rows, then t1
    __shared__ __align__(16) float gshare[2048];          // 8 KB: g in A-frag layout
    const int t = threadIdx.x;
    const int lane = t & 63;
    const int w = t >> 6;
    const int m = lane & 15, q = lane >> 4;
    const int nodeB = blockIdx.x * 16;
    const int node0 = nodeB + w * 4;

    // gather pair0's h1 rows: lane = (nbr m, k-chunk q); 16 floats per node
    float4 hA[8], hB[8];
#pragma unroll
    for (int ng = 0; ng < 2; ++ng) {
        const int c = col[(node0 + ng) * KNB + m];
        const float* hr = H1 + (size_t)c * 64 + q * 8;
        hA[ng * 4 + 0] = *(const float4*)(hr);
        hA[ng * 4 + 1] = *(const float4*)(hr + 4);
        hA[ng * 4 + 2] = *(const float4*)(hr + 32);
        hA[ng * 4 + 3] = *(const float4*)(hr + 36);
    }
    // stage A3 rows (8 KB, NT loads) + W4 HI frags (32 KB)
    {
        const floatx4* asrc = (const floatx4*)(A3 + (size_t)nodeB * 128);
        floatx4* adst = (floatx4*)ashare;
        adst[t]       = __builtin_nontemporal_load(asrc + t);
        adst[t + 256] = __builtin_nontemporal_load(asrc + t + 256);
        const uint4* hsrc = (const uint4*)(WH + (size_t)W4F * 512);
        uint4* wdst = (uint4*)wlds;
#pragma unroll
        for (int i = 0; i < 8; ++i) wdst[t + i * 256] = hsrc[t + i * 256];
    }
    __syncthreads();

    const unsigned short* wlo = WL + (size_t)W4F * 512 + lane * 8;
    float* escr = escratch + w * 2048;

#pragma unroll
    for (int p = 0; p < 2; ++p) {
        // prefetch next pair's h1 gather: in flight across this pair's compute
        if (p == 0) {
#pragma unroll
            for (int ng = 0; ng < 2; ++ng) {
                const int c = col[(node0 + 2 + ng) * KNB + m];
                const float* hr = H1 + (size_t)c * 64 + q * 8;
                hB[ng * 4 + 0] = *(const float4*)(hr);
                hB[ng * 4 + 1] = *(const float4*)(hr + 4);
                hB[ng * 4 + 2] = *(const float4*)(hr + 32);
                hB[ng * 4 + 3] = *(const float4*)(hr + 36);
            }
        }
        floatx4 acc[2][8];
#pragma unroll
        for (int ng = 0; ng < 2; ++ng)
#pragma unroll
            for (int nt = 0; nt < 8; ++nt)
                acc[ng][nt] = (floatx4){0.0f, 0.0f, 0.0f, 0.0f};

#pragma unroll
        for (int h = 0; h < 2; ++h) {
            // B3 on the fly: b3acc[ng][nt] == k2's old acc2[8+h*4+nt] bitwise
            floatx4 b3acc[2][4];
#pragma unroll
            for (int ng = 0; ng < 2; ++ng)
#pragma unroll
                for (int nt = 0; nt < 4; ++nt)
                    b3acc[ng][nt] = (floatx4){0.0f, 0.0f, 0.0f, 0.0f};
#pragma unroll
            for (int kc = 0; kc < 2; ++kc) {
                bf16x8 ah[2], al[2];
#pragma unroll
                for (int ng = 0; ng < 2; ++ng) {
                    float4 h0 = (p == 0) ? hA[ng * 4 + kc * 2]     : hB[ng * 4 + kc * 2];
                    float4 h1v = (p == 0) ? hA[ng * 4 + kc * 2 + 1] : hB[ng * 4 + kc * 2 + 1];
                    split8(h0, h1v, ah[ng], al[ng]);
                }
#pragma unroll
                for (int nt = 0; nt < 4; ++nt) {
                    size_t fb = (size_t)(W3F + kc * 16 + 8 + h * 4 + nt) * 512 + lane * 8;
                    bf16x8 bh = __builtin_bit_cast(bf16x8, *(const uint4*)(WH + fb));
                    bf16x8 bl = __builtin_bit_cast(bf16x8, *(const uint4*)(WL + fb));
#pragma unroll
                    for (int ng = 0; ng < 2; ++ng) {
                        b3acc[ng][nt] = __builtin_amdgcn_mfma_f32_16x16x32_bf16(
                            ah[ng], bh, b3acc[ng][nt], 0, 0, 0);
                        b3acc[ng][nt] = __builtin_amdgcn_mfma_f32_16x16x32_bf16(
                            ah[ng], bl, b3acc[ng][nt], 0, 0, 0);
                        b3acc[ng][nt] = __builtin_amdgcn_mfma_f32_16x16x32_bf16(
                            al[ng], bh, b3acc[ng][nt], 0, 0, 0);
                    }
                }
            }
            // e = relu(A3[node][c] + b3acc) -> escratch in A-frag layout.
            // C layout: row = q*4+r (neighbor), col c = h*64 + nt*16 + m.
#pragma unroll
            for (int ng = 0; ng < 2; ++ng) {
                const int node_l = w * 4 + p * 2 + ng;
#pragma unroll
                for (int nt = 0; nt < 4; ++nt) {
                    const int c = h * 64 + nt * 16 + m;
                    float a3v = ashare[node_l * 128 + c];
                    float* eb = escr + ng * 1024 + (nt >> 1) * 512
                              + ((nt * 2 + (m >> 3)) & 3) * 128 + (m & 7);
#pragma unroll
                    for (int r = 0; r < 4; ++r)
                        eb[(q * 4 + r) * 8] = fmaxf(a3v + b3acc[ng][nt][r], 0.0f);
                }
            }
            // W4 GEMM for kc2 = h*2 + kk (same per-acc order as before)
#pragma unroll
            for (int kk = 0; kk < 2; ++kk) {
                const int kc2 = h * 2 + kk;
                bf16x8 aH[2], aL[2];
#pragma unroll
                for (int ng = 0; ng < 2; ++ng) {
                    const float* ap = escr + ng * 1024 + kk * 512 + lane * 8;
                    split8(*(const float4*)ap, *(const float4*)(ap + 4), aH[ng], aL[ng]);
                }
#pragma unroll
                for (int nt = 0; nt < 8; ++nt) {
                    const int f = kc2 * 8 + nt;
                    bf16x8 bh = __builtin_bit_cast(bf16x8,
                        *(const uint4*)(wlds + f * 512 + lane * 8));
                    bf16x8 bl = __builtin_bit_cast(bf16x8,
                        *(const uint4*)(wlo + (size_t)f * 512));
#pragma unroll
                    for (int ng = 0; ng < 2; ++ng) {
                        acc[ng][nt] = __builtin_amdgcn_mfma_f32_16x16x32_bf16(
                            aH[ng], bh, acc[ng][nt], 0, 0, 0);
                        acc[ng][nt] = __builtin_amdgcn_mfma_f32_16x16x32_bf16(
                            aH[ng], bl, acc[ng][nt], 0, 0, 0);
                        acc[ng][nt] = __builtin_amdgcn_mfma_f32_16x16x32_bf16(
                            aL[ng], bh, acc[ng][nt], 0, 0, 0);
                    }
                }
            }
        }

        // K-max in-register; g = relu(max + b4) -> gshare (A-frag layout)
#pragma unroll
        for (int ng = 0; ng < 2; ++ng) {
            const int mloc = w * 4 + p * 2 + ng;
#pragma unroll
            for (int nt = 0; nt < 8; ++nt) {
                floatx4 a = acc[ng][nt];
                float mm = fmaxf(fmaxf(a[0], a[1]), fmaxf(a[2], a[3]));
                mm = fmaxf(mm, __shfl_xor(mm, 16));
                mm = fmaxf(mm, __shfl_xor(mm, 32));
                if (lane < 16) {
                    int colI = nt * 16 + lane;
                    int kc2 = colI >> 5, q2 = (colI >> 3) & 3, jj = colI & 7;
                    gshare[kc2 * 512 + q2 * 128 + mloc * 8 + jj] =
                        fmaxf(mm + b4[colI], 0.0f);
                }
            }
        }
    }

    // ---- fused node MLP: out = relu(g@W5+b5) @ W6 + b6 ----
    __syncthreads();     // gshare complete; ashare A3 reads done
    // W5 GEMM: wave w -> nt {2w, 2w+1}; W5 frags streamed from L2
    floatx4 acc5[2];
    acc5[0] = (floatx4){0.f, 0.f, 0.f, 0.f};
    acc5[1] = (floatx4){0.f, 0.f, 0.f, 0.f};
#pragma unroll
    for (int kc = 0; kc < 4; ++kc) {
        const float* ap = gshare + kc * 512 + lane * 8;
        bf16x8 ah, al;
        split8(*(const float4*)ap, *(const float4*)(ap + 4), ah, al);
#pragma unroll
        for (int ntl = 0; ntl < 2; ++ntl) {
            int nt = w * 2 + ntl;
            size_t fb = (size_t)(W5F + kc * 8 + nt) * 512 + lane * 8;
            bf16x8 bh = __builtin_bit_cast(bf16x8, *(const uint4*)(WH + fb));
            bf16x8 bl = __builtin_bit_cast(bf16x8, *(const uint4*)(WL + fb));
            acc5[ntl] = __builtin_amdgcn_mfma_f32_16x16x32_bf16(ah, bh, acc5[ntl], 0, 0, 0);
            acc5[ntl] = __builtin_amdgcn_mfma_f32_16x16x32_bf16(ah, bl, acc5[ntl], 0, 0, 0);
            acc5[ntl] = __builtin_amdgcn_mfma_f32_16x16x32_bf16(al, bh, acc5[ntl], 0, 0, 0);
        }
    }
    {   // t1 = relu(acc5 + b5) -> ashare frag kc=w (wave-exclusive region)
        const int qq = lane >> 4, cc = lane & 15;
#pragma unroll
        for (int ntl = 0; ntl < 2; ++ntl) {
            int nt = w * 2 + ntl;
            float bv = b5[nt * 16 + cc];
            int colI = nt * 16 + cc;
            int kc2 = colI >> 5, q2 = (colI >> 3) & 3, jj = cc & 7;
            float* dst = ashare + kc2 * 512 + q2 * 128 + jj;
#pragma unroll
            for (int r = 0; r < 4; ++r)
                dst[(qq * 4 + r) * 8] = fmaxf(acc5[ntl][r] + bv, 0.0f);
        }
    }
    __syncthreads();     // t1 complete across waves
    // W6 GEMM: waves 0..2, nt = w; store out
    if (w < 3) {
        floatx4 acc6 = (floatx4){0.f, 0.f, 0.f, 0.f};
#pragma unroll
        for (int kc = 0; kc < 4; ++kc) {
            const float* ap = ashare + kc * 512 + lane * 8;
            bf16x8 ah, al;
            split8(*(const float4*)ap, *(const float4*)(ap + 4), ah, al);
            size_t fb = (size_t)(W6F + kc * 3 + w) * 512 + lane * 8;
            bf16x8 bh = __builtin_bit_cast(bf16x8, *(const uint4*)(WH + fb));
            bf16x8 bl = __builtin_bit_cast(bf16x8, *(const uint4*)(WL + fb));
            acc6 = __builtin_amdgcn_mfma_f32_16x16x32_bf16(ah, bh, acc6, 0, 0, 0);
            acc6 = __builtin_amdgcn_mfma_f32_16x16x32_bf16(ah, bl, acc6, 0, 0, 0);
            acc6 = __builtin_amdgcn_mfma_f32_16x16x32_bf16(al, bh, acc6, 0, 0, 0);
        }
        const int qq = lane >> 4, cc = lane & 15;
        int n = w * 16 + cc;
        if (n < 40) {
            float bv = b6[n];
#pragma unroll
            for (int r = 0; r < 4; ++r)
                out[(size_t)(nodeB + qq * 4 + r) * 40 + n] = acc6[r] + bv;
        }
    }
}

extern "C" void kernel_launch(void* const* d_in, const int* in_sizes, int n_in,
                              void* d_out, int out_size, void* d_ws, size_t ws_size,
                              hipStream_t stream)
{
    const float* x  = (const float*)d_in[0];
    const int* ei   = (const int*)d_in[1];
    const int* col  = ei + EE;
    const float* W1 = (const float*)d_in[2];
    const float* b1 = (const float*)d_in[3];
    const float* W2 = (const float*)d_in[4];
    const float* b2 = (const float*)d_in[5];
    const float* W3 = (const float*)d_in[6];
    const float* b3 = (const float*)d_in[7];
    const float* W4 = (const float*)d_in[8];
    const float* b4 = (const float*)d_in[9];
    const float* W5 = (const float*)d_in[10];
    const float* b5 = (const float*)d_in[11];
    const float* W6 = (const float*)d_in[12];
    const float* b6 = (const float*)d_in[13];
    float* out = (float*)d_out;

    float* A1 = (float*)d_ws;                    // [N,64]
    float* B1 = A1 + (size_t)NN * 64;            // [N,64]
    float* A3 = B1 + (size_t)NN * 64;            // [N,128]
    float* H1 = A3 + (size_t)NN * 128;           // [N,64] (lives in old B3 slot)
    unsigned short* WH = (unsigned short*)(H1 + (size_t)NN * 128);  // [116*512]
    unsigned short* WL = WH + NFRAG * 512;

    kw_kernel<<<(NFRAG * 64 + 255) / 256, 256, 0, stream>>>(W2, W3, W4, W5, W6, WH, WL);
    k1_kernel<<<NN * 64 / 256, 256, 0, stream>>>(x, W1, b1, A1, B1);
    k2_kernel<<<(NN + 63) / 64, 256, 0, stream>>>(col, A1, B1, WH, WL, b2, b3, A3, H1);
    k3_kernel<<<NN / 16, 256, 0, stream>>>(col, A3, H1, WH, WL, b4, b5, b6, out);
}

// Round 8
// 493.886 us; speedup vs baseline: 1.0026x; 1.0026x over previous
//
#include <hip/hip_runtime.h>

// DGCNN on MI355X — round 19: R18 post-mortem: FETCH 416->201MB as designed,
// but dur 304->408us because the escratch e-write was an 8-way bank conflict
// (bank = r*8 + (m&7): q2*128 and q*32 vanish mod 32) -> SQ_LDS_BANK_CONFLICT
// 3.4M->25.8M. Fix: transposed+swizzled escratch layout, element (nbr,c) at
// c*16 + (nbr ^ 4*((c>>3)&3)):
//   write: r=0..3 contiguous -> 1 ds_write_b128 per (ng,nt); slots
//          (m&1)*16+(q^g)*4, 8 lanes/slot = minimum.
//   read:  (c>>3)&3 = q -> addr kk*512+q*128+j*16+(m^4q); (j,j+1) pairs ->
//          ds_read2_b32, 4 hits/bank per op = minimum.
// Same fp32 values stored/read -> bitwise identical (absmax 4.768372e-07).
// Gather stays h1 (256B/row): FETCH ~201MB. LDS 80KB, 2 blocks/CU.
//   concat(a, b-a) @ W + bias = a @ (Wt-Wb) + b @ Wb + bias
//   conv2 gathers h1 with NODE ids -> only h1[0:N] rows needed

#define NN 100000
#define KNB 16
#define EE (NN * KNB)

// weight fragment bases (units of 512 ushorts = one 64-lane x 8-bf16 frag)
#define W2F 0     // W2  [64][64]   : 2 kc x 4 nt  = 8
#define W3F 8     // W3X [64][256]  : 2 kc x 16 nt = 32  (cols 0-127: W3t-W3b, 128-255: W3b)
#define W4F 40    // W4  [128][128] : 4 kc x 8 nt  = 32
#define W5F 72    // W5  [128][128] : 4 kc x 8 nt  = 32
#define W6F 104   // W6  [128][48p] : 4 kc x 3 nt  = 12
#define NFRAG 116

typedef float floatx4 __attribute__((ext_vector_type(4)));
typedef __bf16 bf16x8 __attribute__((ext_vector_type(8)));

static __device__ __forceinline__ unsigned f2bf_rne_u(float f) {
    unsigned u = __float_as_uint(f);
    return (u + 0x7FFFu + ((u >> 16) & 1u)) >> 16;
}
static __device__ __forceinline__ float bfu2f(unsigned h) {
    return __uint_as_float(h << 16);
}

// split a pair of fp32 into packed bf16 hi (truncate) + bf16 lo (RNE of exact
// residual). hp = {lo16: a_hi, hi16: b_hi}; one v_perm_b32 per pack.
static __device__ __forceinline__ void split_pack2(float a, float b,
                                                   unsigned& hp, unsigned& lp) {
    unsigned ua = __float_as_uint(a), ub = __float_as_uint(b);
    hp = __builtin_amdgcn_perm(ub, ua, 0x07060302u);        // [b.b3 b.b2 a.b3 a.b2]
    float ra = a - __uint_as_float(ua & 0xFFFF0000u);       // exact residual
    float rb = b - __uint_as_float(ub & 0xFFFF0000u);
    unsigned la = __float_as_uint(ra), lb = __float_as_uint(rb);
    la = la + 0x7FFFu + ((la >> 16) & 1u);                  // RNE round point
    lb = lb + 0x7FFFu + ((lb >> 16) & 1u);
    lp = __builtin_amdgcn_perm(lb, la, 0x07060302u);
}

// split 8 fp32 -> bf16x8 hi + bf16x8 lo
static __device__ __forceinline__ void split8(float4 f0, float4 f1,
                                              bf16x8& ah, bf16x8& al) {
    unsigned hd[4], ld[4];
    split_pack2(f0.x, f0.y, hd[0], ld[0]);
    split_pack2(f0.z, f0.w, hd[1], ld[1]);
    split_pack2(f1.x, f1.y, hd[2], ld[2]);
    split_pack2(f1.z, f1.w, hd[3], ld[3]);
    uint4 H = {hd[0], hd[1], hd[2], hd[3]};
    uint4 L = {ld[0], ld[1], ld[2], ld[3]};
    ah = __builtin_bit_cast(bf16x8, H);
    al = __builtin_bit_cast(bf16x8, L);
}

// ---------------- KW: pre-split all weights into frag-ordered bf16 hi/lo ------
// Frag (kc,nt): lane l holds W[kc*32 + (l>>4)*8 + j][nt*16 + (l&15)], j=0..7.
__global__ __launch_bounds__(256) void kw_kernel(
    const float* __restrict__ W2, const float* __restrict__ W3,
    const float* __restrict__ W4, const float* __restrict__ W5,
    const float* __restrict__ W6,
    unsigned short* __restrict__ WH, unsigned short* __restrict__ WL)
{
    int d = blockIdx.x * 256 + threadIdx.x;
    if (d >= NFRAG * 64) return;
    int f = d >> 6, l = d & 63, c = l & 15, q = l >> 4;
    float v[8];
    if (f < W3F) {                    // W2 [64][64]
        int fx = f - W2F, kc = fx >> 2, nt = fx & 3;
        int k0 = kc * 32 + q * 8, n = nt * 16 + c;
#pragma unroll
        for (int j = 0; j < 8; ++j) v[j] = W2[(k0 + j) * 64 + n];
    } else if (f < W4F) {             // W3X [64][256]
        int fx = f - W3F, kc = fx >> 4, nt = fx & 15;
        int k0 = kc * 32 + q * 8, n = nt * 16 + c;
#pragma unroll
        for (int j = 0; j < 8; ++j) {
            int k = k0 + j;
            v[j] = (n < 128) ? (W3[k * 128 + n] - W3[(64 + k) * 128 + n])
                             : W3[(64 + k) * 128 + (n - 128)];
        }
    } else if (f < W5F) {             // W4 [128][128]
        int fx = f - W4F, kc = fx >> 3, nt = fx & 7;
        int k0 = kc * 32 + q * 8, n = nt * 16 + c;
#pragma unroll
        for (int j = 0; j < 8; ++j) v[j] = W4[(k0 + j) * 128 + n];
    } else if (f < W6F) {             // W5 [128][128]
        int fx = f - W5F, kc = fx >> 3, nt = fx & 7;
        int k0 = kc * 32 + q * 8, n = nt * 16 + c;
#pragma unroll
        for (int j = 0; j < 8; ++j) v[j] = W5[(k0 + j) * 128 + n];
    } else {                          // W6 [128][40] padded to 48
        int fx = f - W6F, kc = fx / 3, nt = fx % 3;
        int k0 = kc * 32 + q * 8, n = nt * 16 + c;
#pragma unroll
        for (int j = 0; j < 8; ++j)
            v[j] = (n < 40) ? W6[(k0 + j) * 40 + n] : 0.0f;
    }
    unsigned hs[8], ls[8];
#pragma unroll
    for (int j = 0; j < 8; ++j) {
        unsigned h = f2bf_rne_u(v[j]);
        float r = v[j] - bfu2f(h);
        hs[j] = h;
        ls[j] = f2bf_rne_u(r);
    }
    uint4 H, L;
    H.x = hs[0] | (hs[1] << 16); H.y = hs[2] | (hs[3] << 16);
    H.z = hs[4] | (hs[5] << 16); H.w = hs[6] | (hs[7] << 16);
    L.x = ls[0] | (ls[1] << 16); L.y = ls[2] | (ls[3] << 16);
    L.z = ls[4] | (ls[5] << 16); L.w = ls[6] | (ls[7] << 16);
    *(uint4*)(WH + (size_t)d * 8) = H;
    *(uint4*)(WL + (size_t)d * 8) = L;
}

// ---------------- K1: A1 = x@(W1t-W1b)+b1, B1 = x@W1b ----------------
__global__ __launch_bounds__(256) void k1_kernel(
    const float* __restrict__ x, const float* __restrict__ W1,
    const float* __restrict__ b1, float* __restrict__ A1, float* __restrict__ B1)
{
    int gid = blockIdx.x * 256 + threadIdx.x;
    int n = gid >> 6;
    int j = gid & 63;
    const float* xr = x + n * 16;
    float acc_a = b1[j];
    float acc_b = 0.0f;
#pragma unroll
    for (int k = 0; k < 16; ++k) {
        float xv = xr[k];
        float wt = W1[k * 64 + j];
        float wb = W1[(16 + k) * 64 + j];
        acc_a = fmaf(xv, wt - wb, acc_a);
        acc_b = fmaf(xv, wb, acc_b);
    }
    A1[n * 64 + j] = acc_a;
    B1[n * 64 + j] = acc_b;
}

// ---------------- K2 (MFMA): 64 rows/block --------------------
// GEMM2 halved (nt 0..7, A3 only); exact fp32 h1 stored for k3's regather.
__global__ __launch_bounds__(256) void k2_kernel(
    const int* __restrict__ col,
    const float* __restrict__ A1, const float* __restrict__ B1,
    const unsigned short* __restrict__ WH, const unsigned short* __restrict__ WL,
    const float* __restrict__ b2, const float* __restrict__ b3,
    float* __restrict__ A3, float* __restrict__ H1)
{
    __shared__ __align__(16) float tF[8 * 512];   // 16 KB, frag-contig fp32
    __shared__ __align__(16) float hF[8 * 512];   // 16 KB
    const int t = threadIdx.x;
    const int i0 = blockIdx.x * 64;

    // phase A: t[row] = relu(A1[i>>4] + B1[col[i]]) -> tF frag layout
    {
        const int row = t & 63, part = t >> 6;
        int i = i0 + row;                 // tail reads valid (i < EE), stores guarded
        int nn = i >> 4;
        int ci = col[i];
        const float* ar = A1 + (size_t)nn * 64 + part * 16;
        const float* br = B1 + (size_t)ci * 64 + part * 16;
        int mt = row >> 4, m = row & 15, kc = part >> 1;
        float* base = tF + (mt * 2 + kc) * 512 + m * 8;
#pragma unroll
        for (int h = 0; h < 2; ++h) {
            int qq = (part & 1) * 2 + h;
            float4 a0 = *(const float4*)(ar + h * 8);
            float4 b0 = *(const float4*)(br + h * 8);
            float4 a1 = *(const float4*)(ar + h * 8 + 4);
            float4 b1v = *(const float4*)(br + h * 8 + 4);
            float4 r0, r1;
            r0.x = fmaxf(a0.x + b0.x, 0.0f); r0.y = fmaxf(a0.y + b0.y, 0.0f);
            r0.z = fmaxf(a0.z + b0.z, 0.0f); r0.w = fmaxf(a0.w + b0.w, 0.0f);
            r1.x = fmaxf(a1.x + b1v.x, 0.0f); r1.y = fmaxf(a1.y + b1v.y, 0.0f);
            r1.z = fmaxf(a1.z + b1v.z, 0.0f); r1.w = fmaxf(a1.w + b1v.w, 0.0f);
            *(float4*)(base + qq * 128) = r0;
            *(float4*)(base + qq * 128 + 4) = r1;
        }
    }
    __syncthreads();

    const int w = __builtin_amdgcn_readfirstlane(t >> 6);   // wave = m-tile
    const int lane = t & 63;

    // GEMM1: h-tile rows w*16..+15; acc1[nt=0..3]
    floatx4 acc1[4];
#pragma unroll
    for (int nt = 0; nt < 4; ++nt) acc1[nt] = (floatx4){0.f, 0.f, 0.f, 0.f};
#pragma unroll
    for (int kc = 0; kc < 2; ++kc) {
        const float* ap = tF + (w * 2 + kc) * 512 + lane * 8;
        bf16x8 ah, al;
        split8(*(const float4*)ap, *(const float4*)(ap + 4), ah, al);
#pragma unroll
        for (int nt = 0; nt < 4; ++nt) {
            size_t fb = (size_t)(W2F + kc * 4 + nt) * 512 + lane * 8;
            bf16x8 bh = __builtin_bit_cast(bf16x8, *(const uint4*)(WH + fb));
            bf16x8 bl = __builtin_bit_cast(bf16x8, *(const uint4*)(WL + fb));
            acc1[nt] = __builtin_amdgcn_mfma_f32_16x16x32_bf16(ah, bh, acc1[nt], 0, 0, 0);
            acc1[nt] = __builtin_amdgcn_mfma_f32_16x16x32_bf16(ah, bl, acc1[nt], 0, 0, 0);
            acc1[nt] = __builtin_amdgcn_mfma_f32_16x16x32_bf16(al, bh, acc1[nt], 0, 0, 0);
        }
    }
    // h = relu(acc1 + b2) -> hF frag layout + exact fp32 h1 to global (i<NN)
    {
        const int qq = lane >> 4, cc = lane & 15;
#pragma unroll
        for (int nt = 0; nt < 4; ++nt) {
            float bv = b2[nt * 16 + cc];
            int colIdx = nt * 16 + cc;
            int kc2 = colIdx >> 5, q2 = (colIdx >> 3) & 3, jj = cc & 7;
            float* dst = hF + (w * 2 + kc2) * 512 + q2 * 128 + jj;
#pragma unroll
            for (int r = 0; r < 4; ++r) {
                float hv = fmaxf(acc1[nt][r] + bv, 0.0f);
                dst[(qq * 4 + r) * 8] = hv;
                int i = i0 + w * 16 + qq * 4 + r;
                if (i < NN) H1[(size_t)i * 64 + colIdx] = hv;
            }
        }
    }
    // GEMM2 (halved): [16 x 64] @ W3X[:,0:128]; acc2[nt=0..7] -> A3 only
    floatx4 acc2[8];
#pragma unroll
    for (int nt = 0; nt < 8; ++nt) acc2[nt] = (floatx4){0.f, 0.f, 0.f, 0.f};
#pragma unroll
    for (int kc = 0; kc < 2; ++kc) {
        const float* ap = hF + (w * 2 + kc) * 512 + lane * 8;
        bf16x8 ah, al;
        split8(*(const float4*)ap, *(const float4*)(ap + 4), ah, al);
#pragma unroll
        for (int nt = 0; nt < 8; ++nt) {
            size_t fb = (size_t)(W3F + kc * 16 + nt) * 512 + lane * 8;
            bf16x8 bh = __builtin_bit_cast(bf16x8, *(const uint4*)(WH + fb));
            bf16x8 bl = __builtin_bit_cast(bf16x8, *(const uint4*)(WL + fb));
            acc2[nt] = __builtin_amdgcn_mfma_f32_16x16x32_bf16(ah, bh, acc2[nt], 0, 0, 0);
            acc2[nt] = __builtin_amdgcn_mfma_f32_16x16x32_bf16(ah, bl, acc2[nt], 0, 0, 0);
            acc2[nt] = __builtin_amdgcn_mfma_f32_16x16x32_bf16(al, bh, acc2[nt], 0, 0, 0);
        }
    }
    {
        const int qq = lane >> 4, cc = lane & 15;
#pragma unroll
        for (int nt = 0; nt < 8; ++nt) {
            int n = nt * 16 + cc;
            float bv = b3[n];
#pragma unroll
            for (int r = 0; r < 4; ++r) {
                int i = i0 + w * 16 + qq * 4 + r;
                if (i < NN) A3[(size_t)i * 128 + n] = acc2[nt][r] + bv;
            }
        }
    }
}

// ---------------- K3 (fused): h1-gather -> B3 on the fly -> edge-GEMM ----------
// Block = 16 nodes, 4 waves. escratch layout (conflict-free): element (nbr,c')
// at c'*16 + (nbr ^ 4*((c'>>3)&3)). Write = b128/(ng,nt); read = read2 pairs.
__global__ __launch_bounds__(256, 2) void k3_kernel(
    const int* __restrict__ col,
    const float* __restrict__ A3, const float* __restrict__ H1,
    const unsigned short* __restrict__ WH, const unsigned short* __restrict__ WL,
    const float* __restrict__ b4, const float* __restrict__ b5,
    const float* __restrict__ b6, float* __restrict__ out)
{
    __shared__ __align__(16) unsigned short wlds[16384];  // 32 KB: W4 HI frags
    __shared__ __align__(16) float escratch[8192];        // 32 KB: per-wave e tiles
    __shared__ __align__(16) float ashare[2048];          // 8 KB: A3 rows, then t1
    __shared__ __align__(16) float gshare[2048];          // 8 KB: g in A-frag layout
    const int t = threadIdx.x;
    const int lane = t & 63;
    const int w = t >> 6;
    const int m = lane & 15, q = lane >> 4;
    const int nodeB = blockIdx.x * 16;
    const int node0 = nodeB + w * 4;

    // gather pair0's h1 rows: lane = (nbr m, k-chunk q); 16 floats per node
    float4 hA[8], hB[8];
#pragma unroll
    for (int ng = 0; ng < 2; ++ng) {
        const int c = col[(node0 + ng) * KNB + m];
        const float* hr = H1 + (size_t)c * 64 + q * 8;
        hA[ng * 4 + 0] = *(const float4*)(hr);
        hA[ng * 4 + 1] = *(const float4*)(hr + 4);
        hA[ng * 4 + 2] = *(const float4*)(hr + 32);
        hA[ng * 4 + 3] = *(const float4*)(hr + 36);
    }
    // stage A3 rows (8 KB, NT loads) + W4 HI frags (32 KB)
    {
        const floatx4* asrc = (const floatx4*)(A3 + (size_t)nodeB * 128);
        floatx4* adst = (floatx4*)ashare;
        adst[t]       = __builtin_nontemporal_load(asrc + t);
        adst[t + 256] = __builtin_nontemporal_load(asrc + t + 256);
        const uint4* hsrc = (const uint4*)(WH + (size_t)W4F * 512);
        uint4* wdst = (uint4*)wlds;
#pragma unroll
        for (int i = 0; i < 8; ++i) wdst[t + i * 256] = hsrc[t + i * 256];
    }
    __syncthreads();

    const unsigned short* wlo = WL + (size_t)W4F * 512 + lane * 8;
    float* escr = escratch + w * 2048;

#pragma unroll
    for (int p = 0; p < 2; ++p) {
        // prefetch next pair's h1 gather: in flight across this pair's compute
        if (p == 0) {
#pragma unroll
            for (int ng = 0; ng < 2; ++ng) {
                const int c = col[(node0 + 2 + ng) * KNB + m];
                const float* hr = H1 + (size_t)c * 64 + q * 8;
                hB[ng * 4 + 0] = *(const float4*)(hr);
                hB[ng * 4 + 1] = *(const float4*)(hr + 4);
                hB[ng * 4 + 2] = *(const float4*)(hr + 32);
                hB[ng * 4 + 3] = *(const float4*)(hr + 36);
            }
        }
        floatx4 acc[2][8];
#pragma unroll
        for (int ng = 0; ng < 2; ++ng)
#pragma unroll
            for (int nt = 0; nt < 8; ++nt)
                acc[ng][nt] = (floatx4){0.0f, 0.0f, 0.0f, 0.0f};

#pragma unroll
        for (int h = 0; h < 2; ++h) {
            // B3 on the fly: b3acc[ng][nt] == k2's old acc2[8+h*4+nt] bitwise
            floatx4 b3acc[2][4];
#pragma unroll
            for (int ng = 0; ng < 2; ++ng)
#pragma unroll
                for (int nt = 0; nt < 4; ++nt)
                    b3acc[ng][nt] = (floatx4){0.0f, 0.0f, 0.0f, 0.0f};
#pragma unroll
            for (int kc = 0; kc < 2; ++kc) {
                bf16x8 ah[2], al[2];
#pragma unroll
                for (int ng = 0; ng < 2; ++ng) {
                    float4 h0 = (p == 0) ? hA[ng * 4 + kc * 2]     : hB[ng * 4 + kc * 2];
                    float4 h1v = (p == 0) ? hA[ng * 4 + kc * 2 + 1] : hB[ng * 4 + kc * 2 + 1];
                    split8(h0, h1v, ah[ng], al[ng]);
                }
#pragma unroll
                for (int nt = 0; nt < 4; ++nt) {
                    size_t fb = (size_t)(W3F + kc * 16 + 8 + h * 4 + nt) * 512 + lane * 8;
                    bf16x8 bh = __builtin_bit_cast(bf16x8, *(const uint4*)(WH + fb));
                    bf16x8 bl = __builtin_bit_cast(bf16x8, *(const uint4*)(WL + fb));
#pragma unroll
                    for (int ng = 0; ng < 2; ++ng) {
                        b3acc[ng][nt] = __builtin_amdgcn_mfma_f32_16x16x32_bf16(
                            ah[ng], bh, b3acc[ng][nt], 0, 0, 0);
                        b3acc[ng][nt] = __builtin_amdgcn_mfma_f32_16x16x32_bf16(
                            ah[ng], bl, b3acc[ng][nt], 0, 0, 0);
                        b3acc[ng][nt] = __builtin_amdgcn_mfma_f32_16x16x32_bf16(
                            al[ng], bh, b3acc[ng][nt], 0, 0, 0);
                    }
                }
            }
            // e = relu(A3 + b3acc) -> escratch, transposed+swizzled layout:
            // element (nbr, c') at c'*16 + (nbr ^ 4*((c'>>3)&3)).
            // Lane (q,m) holds nbr = q*4+r, c' = nt*16+m -> one b128 per (ng,nt)
            // at slot (m&1)*16 + (q^g)*4: 8 lanes/slot = conflict-minimum.
#pragma unroll
            for (int ng = 0; ng < 2; ++ng) {
                const int node_l = w * 4 + p * 2 + ng;
                float* eb = escr + ng * 1024;
#pragma unroll
                for (int nt = 0; nt < 4; ++nt) {
                    const int cl = nt * 16 + m;
                    const int g = (nt * 2 + (m >> 3)) & 3;
                    float a3v = ashare[node_l * 128 + h * 64 + cl];
                    floatx4 ev;
#pragma unroll
                    for (int r = 0; r < 4; ++r)
                        ev[r] = fmaxf(a3v + b3acc[ng][nt][r], 0.0f);
                    *(floatx4*)(eb + cl * 16 + ((q ^ g) << 2)) = ev;
                }
            }
            // W4 GEMM for kc2 = h*2 + kk. A-frag read: lane (q,m) wants
            // (nbr=m, c'=kk*32+q*8+j) -> addr kk*512 + q*128 + j*16 + (m^4q);
            // (j,j+1) pairs -> ds_read2_b32, conflict-minimum.
#pragma unroll
            for (int kk = 0; kk < 2; ++kk) {
                const int kc2 = h * 2 + kk;
                bf16x8 aH[2], aL[2];
#pragma unroll
                for (int ng = 0; ng < 2; ++ng) {
                    const float* ap = escr + ng * 1024 + kk * 512 + q * 128 + (m ^ (q << 2));
                    float4 f0, f1;
                    f0.x = ap[0];   f0.y = ap[16];  f0.z = ap[32];  f0.w = ap[48];
                    f1.x = ap[64];  f1.y = ap[80];  f1.z = ap[96];  f1.w = ap[112];
                    split8(f0, f1, aH[ng], aL[ng]);
                }
#pragma unroll
                for (int nt = 0; nt < 8; ++nt) {
                    const int f = kc2 * 8 + nt;
                    bf16x8 bh = __builtin_bit_cast(bf16x8,
                        *(const uint4*)(wlds + f * 512 + lane * 8));
                    bf16x8 bl = __builtin_bit_cast(bf16x8,
                        *(const uint4*)(wlo + (size_t)f * 512));
#pragma unroll
                    for (int ng = 0; ng < 2; ++ng) {
                        acc[ng][nt] = __builtin_amdgcn_mfma_f32_16x16x32_bf16(
                            aH[ng], bh, acc[ng][nt], 0, 0, 0);
                        acc[ng][nt] = __builtin_amdgcn_mfma_f32_16x16x32_bf16(
                            aH[ng], bl, acc[ng][nt], 0, 0, 0);
                        acc[ng][nt] = __builtin_amdgcn_mfma_f32_16x16x32_bf16(
                            aL[ng], bh, acc[ng][nt], 0, 0, 0);
                    }
                }
            }
        }

        // K-max in-register; g = relu(max + b4) -> gshare (A-frag layout)
#pragma unroll
        for (int ng = 0; ng < 2; ++ng) {
            const int mloc = w * 4 + p * 2 + ng;
#pragma unroll
            for (int nt = 0; nt < 8; ++nt) {
                floatx4 a = acc[ng][nt];
                float mm = fmaxf(fmaxf(a[0], a[1]), fmaxf(a[2], a[3]));
                mm = fmaxf(mm, __shfl_xor(mm, 16));
                mm = fmaxf(mm, __shfl_xor(mm, 32));
                if (lane < 16) {
                    int colI = nt * 16 + lane;
                    int kc2 = colI >> 5, q2 = (colI >> 3) & 3, jj = colI & 7;
                    gshare[kc2 * 512 + q2 * 128 + mloc * 8 + jj] =
                        fmaxf(mm + b4[colI], 0.0f);
                }
            }
        }
    }

    // ---- fused node MLP: out = relu(g@W5+b5) @ W6 + b6 ----
    __syncthreads();     // gshare complete; ashare A3 reads done
    // W5 GEMM: wave w -> nt {2w, 2w+1}; W5 frags streamed from L2
    floatx4 acc5[2];
    acc5[0] = (floatx4){0.f, 0.f, 0.f, 0.f};
    acc5[1] = (floatx4){0.f, 0.f, 0.f, 0.f};
#pragma unroll
    for (int kc = 0; kc < 4; ++kc) {
        const float* ap = gshare + kc * 512 + lane * 8;
        bf16x8 ah, al;
        split8(*(const float4*)ap, *(const float4*)(ap + 4), ah, al);
#pragma unroll
        for (int ntl = 0; ntl < 2; ++ntl) {
            int nt = w * 2 + ntl;
            size_t fb = (size_t)(W5F + kc * 8 + nt) * 512 + lane * 8;
            bf16x8 bh = __builtin_bit_cast(bf16x8, *(const uint4*)(WH + fb));
            bf16x8 bl = __builtin_bit_cast(bf16x8, *(const uint4*)(WL + fb));
            acc5[ntl] = __builtin_amdgcn_mfma_f32_16x16x32_bf16(ah, bh, acc5[ntl], 0, 0, 0);
            acc5[ntl] = __builtin_amdgcn_mfma_f32_16x16x32_bf16(ah, bl, acc5[ntl], 0, 0, 0);
            acc5[ntl] = __builtin_amdgcn_mfma_f32_16x16x32_bf16(al, bh, acc5[ntl], 0, 0, 0);
        }
    }
    {   // t1 = relu(acc5 + b5) -> ashare frag kc=w (wave-exclusive region)
        const int qq = lane >> 4, cc = lane & 15;
#pragma unroll
        for (int ntl = 0; ntl < 2; ++ntl) {
            int nt = w * 2 + ntl;
            float bv = b5[nt * 16 + cc];
            int colI = nt * 16 + cc;
            int kc2 = colI >> 5, q2 = (colI >> 3) & 3, jj = cc & 7;
            float* dst = ashare + kc2 * 512 + q2 * 128 + jj;
#pragma unroll
            for (int r = 0; r < 4; ++r)
                dst[(qq * 4 + r) * 8] = fmaxf(acc5[ntl][r] + bv, 0.0f);
        }
    }
    __syncthreads();     // t1 complete across waves
    // W6 GEMM: waves 0..2, nt = w; store out
    if (w < 3) {
        floatx4 acc6 = (floatx4){0.f, 0.f, 0.f, 0.f};
#pragma unroll
        for (int kc = 0; kc < 4; ++kc) {
            const float* ap = ashare + kc * 512 + lane * 8;
            bf16x8 ah, al;
            split8(*(const float4*)ap, *(const float4*)(ap + 4), ah, al);
            size_t fb = (size_t)(W6F + kc * 3 + w) * 512 + lane * 8;
            bf16x8 bh = __builtin_bit_cast(bf16x8, *(const uint4*)(WH + fb));
            bf16x8 bl = __builtin_bit_cast(bf16x8, *(const uint4*)(WL + fb));
            acc6 = __builtin_amdgcn_mfma_f32_16x16x32_bf16(ah, bh, acc6, 0, 0, 0);
            acc6 = __builtin_amdgcn_mfma_f32_16x16x32_bf16(ah, bl, acc6, 0, 0, 0);
            acc6 = __builtin_amdgcn_mfma_f32_16x16x32_bf16(al, bh, acc6, 0, 0, 0);
        }
        const int qq = lane >> 4, cc = lane & 15;
        int n = w * 16 + cc;
        if (n < 40) {
            float bv = b6[n];
#pragma unroll
            for (int r = 0; r < 4; ++r)
                out[(size_t)(nodeB + qq * 4 + r) * 40 + n] = acc6[r] + bv;
        }
    }
}

extern "C" void kernel_launch(void* const* d_in, const int* in_sizes, int n_in,
                              void* d_out, int out_size, void* d_ws, size_t ws_size,
                              hipStream_t stream)
{
    const float* x  = (const float*)d_in[0];
    const int* ei   = (const int*)d_in[1];
    const int* col  = ei + EE;
    const float* W1 = (const float*)d_in[2];
    const float* b1 = (const float*)d_in[3];
    const float* W2 = (const float*)d_in[4];
    const float* b2 = (const float*)d_in[5];
    const float* W3 = (const float*)d_in[6];
    const float* b3 = (const float*)d_in[7];
    const float* W4 = (const float*)d_in[8];
    const float* b4 = (const float*)d_in[9];
    const float* W5 = (const float*)d_in[10];
    const float* b5 = (const float*)d_in[11];
    const float* W6 = (const float*)d_in[12];
    const float* b6 = (const float*)d_in[13];
    float* out = (float*)d_out;

    float* A1 = (float*)d_ws;                    // [N,64]
    float* B1 = A1 + (size_t)NN * 64;            // [N,64]
    float* A3 = B1 + (size_t)NN * 64;            // [N,128]
    float* H1 = A3 + (size_t)NN * 128;           // [N,64] (lives in old B3 slot)
    unsigned short* WH = (unsigned short*)(H1 + (size_t)NN * 128);  // [116*512]
    unsigned short* WL = WH + NFRAG * 512;

    kw_kernel<<<(NFRAG * 64 + 255) / 256, 256, 0, stream>>>(W2, W3, W4, W5, W6, WH, WL);
    k1_kernel<<<NN * 64 / 256, 256, 0, stream>>>(x, W1, b1, A1, B1);
    k2_kernel<<<(NN + 63) / 64, 256, 0, stream>>>(col, A1, B1, WH, WL, b2, b3, A3, H1);
    k3_kernel<<<NN / 16, 256, 0, stream>>>(col, A3, H1, WH, WL, b4, b5, b6, out);
}